// Round 5
// baseline (289.443 us; speedup 1.0000x reference)
//
#include <hip/hip_runtime.h>
#include <hip/hip_bf16.h>

// B=32, S=2048, H=512, fp32 in/out.
// scores = tanh(Y@W + b).w -> softmax(S) -> c_star = alpha@Y
// GEMM: M-tile 32 x FULL N=512 per block -> Y read exactly once (128MB).
// fp16 MFMA (W fp16 RNE), A prefetch-pipelined fp32->fp16, B via swizzled
// llds from L2-hot Wt. Scores complete per block (no atomics/partials).

#define Bsz 32
#define Ssz 2048
#define Hsz 512
#define Msz (Bsz * Ssz)   // 65536

using half8   = __attribute__((ext_vector_type(8))) _Float16;
using half4   = __attribute__((ext_vector_type(4))) _Float16;
using floatx4 = __attribute__((ext_vector_type(4))) float;

__device__ __forceinline__ void llds(_Float16* l, const _Float16* g) {
  __builtin_amdgcn_global_load_lds((const __attribute__((address_space(1))) void*)g,
                                   (__attribute__((address_space(3))) void*)l, 16, 0, 0);
}

__device__ __forceinline__ float fast_tanh(float x) {
  const float e = __expf(2.f * x);
  return 1.f - 2.f / (e + 1.f);
}

// ---- W[k][n] fp32 -> Wt[n][k] fp16 (transpose + RNE cast) ----
__global__ __launch_bounds__(256) void wsplit_k(const float* __restrict__ W,
                                                _Float16* __restrict__ Wt) {
  __shared__ float tile[32][33];
  const int bx = blockIdx.x & 15, by = blockIdx.x >> 4;
  const int tx = threadIdx.x & 31, ty = threadIdx.x >> 5;
#pragma unroll
  for (int i = 0; i < 4; ++i)
    tile[ty + 8 * i][tx] = W[(size_t)(by * 32 + ty + 8 * i) * Hsz + bx * 32 + tx];
  __syncthreads();
#pragma unroll
  for (int i = 0; i < 4; ++i) {
    const int n = bx * 32 + ty + 8 * i;
    const int k = by * 32 + tx;
    Wt[(size_t)n * Hsz + k] = (_Float16)tile[tx][ty + 8 * i];
  }
}

// ---- GEMM: 32 rows x all 512 cols per block; scores written directly ----
__global__ __launch_bounds__(256) void gemm_score_k(const float* __restrict__ Y,
                                                    const _Float16* __restrict__ Wt,
                                                    const float* __restrict__ bvec,
                                                    const float* __restrict__ wvec,
                                                    float* __restrict__ scores) {
  __shared__ __align__(16) _Float16 As[32 * 32];    // 2 KB
  __shared__ __align__(16) _Float16 Bs[512 * 32];   // 32 KB
  const int tid = threadIdx.x;
  const int lane = tid & 63, wv = tid >> 6;
  const int lr = lane & 15, lq = lane >> 4;
  const int mblk = blockIdx.x;  // rows mblk*32 .. +32

  floatx4 acc[2][8];
#pragma unroll
  for (int rf = 0; rf < 2; ++rf)
#pragma unroll
    for (int cf = 0; cf < 8; ++cf)
      acc[rf][cf] = (floatx4){0.f, 0.f, 0.f, 0.f};

  // A staging (thread-constant): thread -> (row, 4-float segment)
  const int arow = tid >> 3, aseg = tid & 7;
  const float* aga = Y + ((size_t)(mblk * 32 + arow)) * Hsz + aseg * 4;
  const int aslot = (aseg >> 1) ^ ((arow >> 1) & 3);
  const int awoff = arow * 32 + aslot * 8 + (aseg & 1) * 4;

  // B staging: 2048 chunks of 16B, 8 llds/thread, gptr-swizzled within 64B row-chunk
  auto stageB = [&](int it) {
    const int k0 = it * 32;
#pragma unroll
    for (int i = 0; i < 8; ++i) {
      const int cbase = i * 256 + wv * 64;
      const int c = cbase + lane;
      const int brow = c >> 2;
      const int gpart = (c & 3) ^ ((brow >> 1) & 3);
      llds(&Bs[cbase * 8], Wt + (size_t)brow * Hsz + (k0 + gpart * 8));
    }
  };
  auto writeA = [&](const float4 f) {
    half4 h;
    h[0] = (_Float16)f.x; h[1] = (_Float16)f.y;
    h[2] = (_Float16)f.z; h[3] = (_Float16)f.w;
    *(half4*)&As[awoff] = h;   // ds_write_b64
  };

  // prologue: tile 0
  float4 fa = *(const float4*)aga;
  stageB(0);
  writeA(fa);
  __syncthreads();

  for (int it = 0; it < 16; ++it) {
    half8 a[2];
#pragma unroll
    for (int rf = 0; rf < 2; ++rf) {
      const int ar = rf * 16 + lr;
      a[rf] = *(const half8*)&As[ar * 32 + (lq ^ ((ar >> 1) & 3)) * 8];
    }
    if (it < 15)
      fa = *(const float4*)(aga + (it + 1) * 32);  // async; waited in writeA

#pragma unroll
    for (int cf = 0; cf < 8; ++cf) {
      const int nr = wv * 128 + cf * 16 + lr;
      const half8 b = *(const half8*)&Bs[nr * 32 + (lq ^ ((nr >> 1) & 3)) * 8];
      acc[0][cf] = __builtin_amdgcn_mfma_f32_16x16x32_f16(a[0], b, acc[0][cf], 0, 0, 0);
      acc[1][cf] = __builtin_amdgcn_mfma_f32_16x16x32_f16(a[1], b, acc[1][cf], 0, 0, 0);
    }
    if (it < 15) {
      __syncthreads();        // LDS consumption done
      stageB(it + 1);
      writeA(fa);             // vmcnt wait lands here, after MFMAs
      __syncthreads();        // staging visible
    }
  }

  // Epilogue: score[row] = sum over all 512 cols of tanh(pre+b)*w.
  // Wave wv owns cols wv*128..+128; reduce lr(16) by shuffle, waves via LDS.
  float bb[8], ww[8];
#pragma unroll
  for (int cf = 0; cf < 8; ++cf) {
    const int col = wv * 128 + cf * 16 + lr;
    bb[cf] = bvec[col];
    ww[cf] = wvec[col];
  }
  __syncthreads();
  float* red = (float*)As;   // 32 rows x 4 waves
#pragma unroll
  for (int rf = 0; rf < 2; ++rf) {
#pragma unroll
    for (int r = 0; r < 4; ++r) {
      float v = 0.f;
#pragma unroll
      for (int cf = 0; cf < 8; ++cf)
        v += fast_tanh(acc[rf][cf][r] + bb[cf]) * ww[cf];
      v += __shfl_xor(v, 1, 16);
      v += __shfl_xor(v, 2, 16);
      v += __shfl_xor(v, 4, 16);
      v += __shfl_xor(v, 8, 16);
      if (lr == 0)
        red[(rf * 16 + lq * 4 + r) * 4 + wv] = v;
    }
  }
  __syncthreads();
  if (tid < 32)
    scores[mblk * 32 + tid] =
        red[tid * 4] + red[tid * 4 + 1] + red[tid * 4 + 2] + red[tid * 4 + 3];
}

// ---- softmax over S ----
__global__ __launch_bounds__(256) void softmax_k(const float* __restrict__ scores,
                                                 const float* __restrict__ mask,
                                                 float* __restrict__ alpha) {
  const int b = blockIdx.x, t = threadIdx.x;
  const int lane = t & 63, wv = t >> 6;
  float s[8];
  float mx = -3.4e38f;
#pragma unroll
  for (int i = 0; i < 8; ++i) {
    const int idx = b * Ssz + i * 256 + t;
    float v = scores[idx] - 1000.f * (1.f - mask[idx]);
    s[i] = v;
    mx = fmaxf(mx, v);
  }
  for (int off = 32; off > 0; off >>= 1) mx = fmaxf(mx, __shfl_xor(mx, off, 64));
  __shared__ float rm[4], rs[4];
  if (lane == 0) rm[wv] = mx;
  __syncthreads();
  mx = fmaxf(fmaxf(rm[0], rm[1]), fmaxf(rm[2], rm[3]));
  float sum = 0.f;
#pragma unroll
  for (int i = 0; i < 8; ++i) {
    s[i] = __expf(s[i] - mx);
    sum += s[i];
  }
  for (int off = 32; off > 0; off >>= 1) sum += __shfl_xor(sum, off, 64);
  if (lane == 0) rs[wv] = sum;
  __syncthreads();
  sum = rs[0] + rs[1] + rs[2] + rs[3];
  const float inv = 1.f / sum;
#pragma unroll
  for (int i = 0; i < 8; ++i) alpha[b * Ssz + i * 256 + t] = s[i] * inv;
}

// ---- stage 1: partial sums of alpha*Y over 64-row slabs (contiguous 128KB) ----
__global__ __launch_bounds__(256) void wsum1_k(const float* __restrict__ alpha,
                                               const float* __restrict__ Y,
                                               float* __restrict__ partial) {
  const int b = blockIdx.x >> 5, sc = blockIdx.x & 31;
  const int t = threadIdx.x, lane = t & 63, wv = t >> 6;
  __shared__ float part[4 * 512];
  const int s0 = sc * 64 + wv * 16;
  const float* al = alpha + b * Ssz + s0;
  const float4* Yb = (const float4*)(Y + ((size_t)b * Ssz + s0) * Hsz);
  float a0 = 0.f, a1 = 0.f, a2 = 0.f, a3 = 0.f, a4 = 0.f, a5 = 0.f, a6 = 0.f, a7 = 0.f;
#pragma unroll 4
  for (int r = 0; r < 16; ++r) {
    const float a = al[r];
    const float4 y0 = Yb[r * 128 + lane * 2];
    const float4 y1 = Yb[r * 128 + lane * 2 + 1];
    a0 = fmaf(a, y0.x, a0); a1 = fmaf(a, y0.y, a1);
    a2 = fmaf(a, y0.z, a2); a3 = fmaf(a, y0.w, a3);
    a4 = fmaf(a, y1.x, a4); a5 = fmaf(a, y1.y, a5);
    a6 = fmaf(a, y1.z, a6); a7 = fmaf(a, y1.w, a7);
  }
  part[wv * 512 + 0 * 64 + lane] = a0;
  part[wv * 512 + 1 * 64 + lane] = a1;
  part[wv * 512 + 2 * 64 + lane] = a2;
  part[wv * 512 + 3 * 64 + lane] = a3;
  part[wv * 512 + 4 * 64 + lane] = a4;
  part[wv * 512 + 5 * 64 + lane] = a5;
  part[wv * 512 + 6 * 64 + lane] = a6;
  part[wv * 512 + 7 * 64 + lane] = a7;
  __syncthreads();
#pragma unroll
  for (int i = 0; i < 2; ++i) {
    const int h = i * 256 + t;
    const int idx = (h & 7) * 64 + (h >> 3);
    partial[((size_t)(b * 32 + sc)) * Hsz + h] =
        part[idx] + part[512 + idx] + part[1024 + idx] + part[1536 + idx];
  }
}

// ---- stage 2: out[b][h] = sum over 32 sc of partial ----
__global__ __launch_bounds__(256) void wsum2_k(const float* __restrict__ partial,
                                               float* __restrict__ out) {
  const int b = blockIdx.x >> 1;
  const int h = (blockIdx.x & 1) * 256 + threadIdx.x;
  float s = 0.f;
#pragma unroll 8
  for (int sc = 0; sc < 32; ++sc)
    s += partial[((size_t)(b * 32 + sc)) * Hsz + h];
  out[b * Hsz + h] = s;
}

extern "C" void kernel_launch(void* const* d_in, const int* in_sizes, int n_in,
                              void* d_out, int out_size, void* d_ws, size_t ws_size,
                              hipStream_t stream) {
  (void)in_sizes; (void)n_in; (void)out_size; (void)ws_size;
  const float* Y    = (const float*)d_in[0];
  const float* mask = (const float*)d_in[1];
  const float* W    = (const float*)d_in[2];
  const float* bvec = (const float*)d_in[3];
  const float* wvec = (const float*)d_in[4];
  float* out = (float*)d_out;

  char* ws = (char*)d_ws;
  _Float16* Wt   = (_Float16*)ws;                            // 512 KB
  float* scores  = (float*)(ws + ((size_t)1 << 20));         // 256 KB
  float* alpha   = (float*)(ws + ((size_t)1 << 20) + (256u << 10)); // 256 KB
  float* partial = (float*)(ws + ((size_t)2 << 20));         // 2 MB

  wsplit_k<<<256, 256, 0, stream>>>(W, Wt);
  gemm_score_k<<<Msz / 32, 256, 0, stream>>>(Y, Wt, bvec, wvec, scores);
  softmax_k<<<Bsz, 256, 0, stream>>>(scores, mask, alpha);
  wsum1_k<<<Bsz * 32, 256, 0, stream>>>(alpha, Y, partial);
  wsum2_k<<<Bsz * 2, 256, 0, stream>>>(partial, out);
}

// Round 6
// 273.384 us; speedup vs baseline: 1.0587x; 1.0587x over previous
//
#include <hip/hip_runtime.h>
#include <hip/hip_bf16.h>

// B=32, S=2048, H=512, fp32 in/out.
// scores = tanh(Y@W + b).w -> softmax(S) -> c_star = alpha@Y
// GEMM: m97-style 128x128 tile, BK=32. A staged as RAW fp32 via llds
// (no register global loads in the K-loop -> barrier vmcnt drain only
// waits llds), converted fp32->fp16 RNE after ds_read, in registers.
// Both LDS tiles chunk-XOR swizzled via gptr permutation -> 2 lanes/bank.
// Tail: softmax (sums 4 col-partials) + two-stage contiguous wsum.

#define Bsz 32
#define Ssz 2048
#define Hsz 512
#define Msz (Bsz * Ssz)   // 65536

using half8   = __attribute__((ext_vector_type(8))) _Float16;
using floatx4 = __attribute__((ext_vector_type(4))) float;

__device__ __forceinline__ void llds16(void* l, const void* g) {
  __builtin_amdgcn_global_load_lds((const __attribute__((address_space(1))) void*)g,
                                   (__attribute__((address_space(3))) void*)l, 16, 0, 0);
}

__device__ __forceinline__ float fast_tanh(float x) {
  const float e = __expf(2.f * x);
  return 1.f - 2.f / (e + 1.f);
}

// ---- W[k][n] fp32 -> Wt[n][k] fp16 (transpose + RNE cast) ----
__global__ __launch_bounds__(256) void wsplit_k(const float* __restrict__ W,
                                                _Float16* __restrict__ Wt) {
  __shared__ float tile[32][33];
  const int bx = blockIdx.x & 15, by = blockIdx.x >> 4;
  const int tx = threadIdx.x & 31, ty = threadIdx.x >> 5;
#pragma unroll
  for (int i = 0; i < 4; ++i)
    tile[ty + 8 * i][tx] = W[(size_t)(by * 32 + ty + 8 * i) * Hsz + bx * 32 + tx];
  __syncthreads();
#pragma unroll
  for (int i = 0; i < 4; ++i) {
    const int n = bx * 32 + ty + 8 * i;
    const int k = by * 32 + tx;
    Wt[(size_t)n * Hsz + k] = (_Float16)tile[tx][ty + 8 * i];
  }
}

// ---- GEMM + tanh.w partial-score epilogue ----
__global__ __launch_bounds__(256) void gemm_score_k(const float* __restrict__ Y,
                                                    const _Float16* __restrict__ Wt,
                                                    const float* __restrict__ bvec,
                                                    const float* __restrict__ wvec,
                                                    float* __restrict__ scores4) {
  __shared__ __align__(16) float    As[128 * 32];   // 16 KB fp32, chunk-swizzled
  __shared__ __align__(16) _Float16 Bs[128 * 32];   // 8 KB fp16, chunk-swizzled
  const int tid = threadIdx.x;
  const int lane = tid & 63, wv = tid >> 6;
  const int wr = wv >> 1, wc = wv & 1;
  const int lr = lane & 15, lq = lane >> 4;
  // XCD-aware decode: 4 nblk-siblings of one mblk share (g&7) -> same XCD L2.
  const int g = blockIdx.x;
  const int x = g & 7, q = g >> 3;
  const int nblk = q & 3;
  const int mblk = (q >> 2) * 8 + x;

  floatx4 acc[4][4];
#pragma unroll
  for (int rf = 0; rf < 4; ++rf)
#pragma unroll
    for (int cf = 0; cf < 4; ++cf)
      acc[rf][cf] = (floatx4){0.f, 0.f, 0.f, 0.f};

  const float* aY = Y + (size_t)mblk * 128 * Hsz;
  const _Float16* bW = Wt + (size_t)nblk * 128 * Hsz;

  for (int it = 0; it < 16; ++it) {
    const int k0 = it * 32;
    // A: 1024 chunks of 16B (row=chunk>>3). gptr permuted within the row's
    // 128B window: at LDS slot s we store global chunk s^(row&7).
#pragma unroll
    for (int i = 0; i < 4; ++i) {
      const int cb = i * 256 + wv * 64;        // wave-uniform chunk base
      const int p = cb + lane;
      const int row = p >> 3;
      const int gc = (p & 7) ^ (row & 7);
      llds16(&As[cb * 4], aY + (size_t)row * Hsz + k0 + gc * 4);
    }
    // B: 512 chunks (row=chunk>>2), permuted within the row's 64B window.
#pragma unroll
    for (int i = 0; i < 2; ++i) {
      const int cb = i * 256 + wv * 64;
      const int p = cb + lane;
      const int row = p >> 2;
      const int gc = (p & 3) ^ ((row >> 1) & 3);
      llds16(&Bs[cb * 8], bW + (size_t)row * Hsz + k0 + gc * 8);
    }
    __syncthreads();   // vmcnt drain waits only the llds above

    half8 a[4], bf[4];
#pragma unroll
    for (int rf = 0; rf < 4; ++rf) {
      const int ar = wr * 64 + rf * 16 + lr;
      const int s0 = (lq * 2) ^ (ar & 7);      // slot of k-chunk lq*2
      const float4 flo = *(const float4*)&As[ar * 32 + s0 * 4];
      const float4 fhi = *(const float4*)&As[ar * 32 + (s0 ^ 1) * 4];
      half8 h;
      h[0] = (_Float16)flo.x; h[1] = (_Float16)flo.y;
      h[2] = (_Float16)flo.z; h[3] = (_Float16)flo.w;
      h[4] = (_Float16)fhi.x; h[5] = (_Float16)fhi.y;
      h[6] = (_Float16)fhi.z; h[7] = (_Float16)fhi.w;
      a[rf] = h;
    }
#pragma unroll
    for (int cf = 0; cf < 4; ++cf) {
      const int nr = wc * 64 + cf * 16 + lr;
      bf[cf] = *(const half8*)&Bs[nr * 32 + (lq ^ ((nr >> 1) & 3)) * 8];
    }
#pragma unroll
    for (int rf = 0; rf < 4; ++rf)
#pragma unroll
      for (int cf = 0; cf < 4; ++cf)
        acc[rf][cf] = __builtin_amdgcn_mfma_f32_16x16x32_f16(a[rf], bf[cf], acc[rf][cf], 0, 0, 0);
    __syncthreads();
  }

  // Epilogue: v = sum_cols tanh(pre+b)*w; 16-lane shuffle reduce;
  // combine 2 col-waves via LDS; non-atomic per-nblk partial store.
  float bb[4], ww[4];
  const int colbase = nblk * 128 + wc * 64;
#pragma unroll
  for (int cf = 0; cf < 4; ++cf) {
    const int col = colbase + cf * 16 + lr;
    bb[cf] = bvec[col];
    ww[cf] = wvec[col];
  }
  float* red = (float*)As;  // 256 floats, reuse LDS
#pragma unroll
  for (int rf = 0; rf < 4; ++rf) {
#pragma unroll
    for (int r = 0; r < 4; ++r) {
      float v = 0.f;
#pragma unroll
      for (int cf = 0; cf < 4; ++cf)
        v += fast_tanh(acc[rf][cf][r] + bb[cf]) * ww[cf];
      v += __shfl_xor(v, 1, 16);
      v += __shfl_xor(v, 2, 16);
      v += __shfl_xor(v, 4, 16);
      v += __shfl_xor(v, 8, 16);
      if (lr == 0)
        red[(wr * 64 + rf * 16 + lq * 4 + r) * 2 + wc] = v;
    }
  }
  __syncthreads();
  if (tid < 128)
    scores4[(size_t)nblk * Msz + mblk * 128 + tid] = red[2 * tid] + red[2 * tid + 1];
}

// ---- softmax over S, summing 4 nblk partials -> alpha ----
__global__ __launch_bounds__(256) void softmax_k(const float* __restrict__ scores4,
                                                 const float* __restrict__ mask,
                                                 float* __restrict__ alpha) {
  const int b = blockIdx.x, t = threadIdx.x;
  const int lane = t & 63, wv = t >> 6;
  float s[8];
  float mx = -3.4e38f;
#pragma unroll
  for (int i = 0; i < 8; ++i) {
    const int idx = b * Ssz + i * 256 + t;
    float v = scores4[idx] + scores4[Msz + idx] + scores4[2 * Msz + idx] + scores4[3 * Msz + idx];
    v -= 1000.f * (1.f - mask[idx]);
    s[i] = v;
    mx = fmaxf(mx, v);
  }
  for (int off = 32; off > 0; off >>= 1) mx = fmaxf(mx, __shfl_xor(mx, off, 64));
  __shared__ float rm[4], rs[4];
  if (lane == 0) rm[wv] = mx;
  __syncthreads();
  mx = fmaxf(fmaxf(rm[0], rm[1]), fmaxf(rm[2], rm[3]));
  float sum = 0.f;
#pragma unroll
  for (int i = 0; i < 8; ++i) {
    s[i] = __expf(s[i] - mx);
    sum += s[i];
  }
  for (int off = 32; off > 0; off >>= 1) sum += __shfl_xor(sum, off, 64);
  if (lane == 0) rs[wv] = sum;
  __syncthreads();
  sum = rs[0] + rs[1] + rs[2] + rs[3];
  const float inv = 1.f / sum;
#pragma unroll
  for (int i = 0; i < 8; ++i) alpha[b * Ssz + i * 256 + t] = s[i] * inv;
}

// ---- stage 1: partial sums of alpha*Y over 64-row slabs (contiguous 128KB) ----
__global__ __launch_bounds__(256) void wsum1_k(const float* __restrict__ alpha,
                                               const float* __restrict__ Y,
                                               float* __restrict__ partial) {
  const int b = blockIdx.x >> 5, sc = blockIdx.x & 31;
  const int t = threadIdx.x, lane = t & 63, wv = t >> 6;
  __shared__ float part[4 * 512];
  const int s0 = sc * 64 + wv * 16;
  const float* al = alpha + b * Ssz + s0;
  const float4* Yb = (const float4*)(Y + ((size_t)b * Ssz + s0) * Hsz);
  float a0 = 0.f, a1 = 0.f, a2 = 0.f, a3 = 0.f, a4 = 0.f, a5 = 0.f, a6 = 0.f, a7 = 0.f;
#pragma unroll 4
  for (int r = 0; r < 16; ++r) {
    const float a = al[r];
    const float4 y0 = Yb[r * 128 + lane * 2];
    const float4 y1 = Yb[r * 128 + lane * 2 + 1];
    a0 = fmaf(a, y0.x, a0); a1 = fmaf(a, y0.y, a1);
    a2 = fmaf(a, y0.z, a2); a3 = fmaf(a, y0.w, a3);
    a4 = fmaf(a, y1.x, a4); a5 = fmaf(a, y1.y, a5);
    a6 = fmaf(a, y1.z, a6); a7 = fmaf(a, y1.w, a7);
  }
  part[wv * 512 + 0 * 64 + lane] = a0;
  part[wv * 512 + 1 * 64 + lane] = a1;
  part[wv * 512 + 2 * 64 + lane] = a2;
  part[wv * 512 + 3 * 64 + lane] = a3;
  part[wv * 512 + 4 * 64 + lane] = a4;
  part[wv * 512 + 5 * 64 + lane] = a5;
  part[wv * 512 + 6 * 64 + lane] = a6;
  part[wv * 512 + 7 * 64 + lane] = a7;
  __syncthreads();
#pragma unroll
  for (int i = 0; i < 2; ++i) {
    const int h = i * 256 + t;
    const int idx = (h & 7) * 64 + (h >> 3);
    partial[((size_t)(b * 32 + sc)) * Hsz + h] =
        part[idx] + part[512 + idx] + part[1024 + idx] + part[1536 + idx];
  }
}

// ---- stage 2: out[b][h] = sum over 32 sc of partial ----
__global__ __launch_bounds__(256) void wsum2_k(const float* __restrict__ partial,
                                               float* __restrict__ out) {
  const int b = blockIdx.x >> 1;
  const int h = (blockIdx.x & 1) * 256 + threadIdx.x;
  float s = 0.f;
#pragma unroll 8
  for (int sc = 0; sc < 32; ++sc)
    s += partial[((size_t)(b * 32 + sc)) * Hsz + h];
  out[b * Hsz + h] = s;
}

extern "C" void kernel_launch(void* const* d_in, const int* in_sizes, int n_in,
                              void* d_out, int out_size, void* d_ws, size_t ws_size,
                              hipStream_t stream) {
  (void)in_sizes; (void)n_in; (void)out_size; (void)ws_size;
  const float* Y    = (const float*)d_in[0];
  const float* mask = (const float*)d_in[1];
  const float* W    = (const float*)d_in[2];
  const float* bvec = (const float*)d_in[3];
  const float* wvec = (const float*)d_in[4];
  float* out = (float*)d_out;

  char* ws = (char*)d_ws;
  _Float16* Wt   = (_Float16*)ws;                            // 512 KB
  float* scores4 = (float*)(ws + ((size_t)1 << 20));         // 1 MB (4 partials)
  float* alpha   = (float*)(ws + ((size_t)2 << 20));         // 256 KB
  float* partial = (float*)(ws + ((size_t)3 << 20));         // 2 MB

  wsplit_k<<<256, 256, 0, stream>>>(W, Wt);
  gemm_score_k<<<(Msz / 128) * 4, 256, 0, stream>>>(Y, Wt, bvec, wvec, scores4);
  softmax_k<<<Bsz, 256, 0, stream>>>(scores4, mask, alpha);
  wsum1_k<<<Bsz * 32, 256, 0, stream>>>(alpha, Y, partial);
  wsum2_k<<<Bsz * 2, 256, 0, stream>>>(partial, out);
}